// Round 1
// baseline (611.013 us; speedup 1.0000x reference)
//
#include <hip/hip_runtime.h>

// ---------- types ----------
typedef _Float16 half8  __attribute__((ext_vector_type(8)));
typedef _Float16 half4v __attribute__((ext_vector_type(4)));
typedef _Float16 half2v __attribute__((ext_vector_type(2)));
typedef float    float4v __attribute__((ext_vector_type(4)));

__device__ __forceinline__ float hsig(float x) {
  return fminf(fmaxf(fmaf(x, 0.2f, 0.5f), 0.0f), 1.0f);
}

// ---------- prep: A-pair build: d1 = f16(src); d2 = f16(src) with cols j<2048 negated ----------
__global__ __launch_bounds__(256) void cvt_pair(const float* __restrict__ src,
                                                _Float16* __restrict__ d1,
                                                _Float16* __restrict__ d2) {
  int i = blockIdx.x * blockDim.x + threadIdx.x;   // 1,048,576 float4 groups
  int base = i * 4;
  int j = base & 4095;
  float s = (j < 2048) ? -1.0f : 1.0f;
  float4 v = *(const float4*)&src[base];
  half4v h1 = {(_Float16)v.x, (_Float16)v.y, (_Float16)v.z, (_Float16)v.w};
  half4v h2 = {(_Float16)(s * v.x), (_Float16)(s * v.y), (_Float16)(s * v.z), (_Float16)(s * v.w)};
  *(half4v*)&d1[base] = h1;
  *(half4v*)&d2[base] = h2;
}

// ---------- prep: transpose+cast the 4 raw weight matrices (2048 x 6144 f32) -> (6144 x 2048 f16) ----------
__global__ __launch_bounds__(256) void transpose_cast(
    const float* __restrict__ s0, const float* __restrict__ s1,
    const float* __restrict__ s2, const float* __restrict__ s3,
    _Float16* __restrict__ d0, _Float16* __restrict__ d1m,
    _Float16* __restrict__ d2m, _Float16* __restrict__ d3m)
{
  __shared__ float tile[64][65];
  const float* srcs[4] = {s0, s1, s2, s3};
  _Float16*    dsts[4] = {d0, d1m, d2m, d3m};
  const float* src = srcs[blockIdx.z];
  _Float16*    dst = dsts[blockIdx.z];

  const int tid = threadIdx.x;
  const int k0 = blockIdx.x * 64;   // 0..2047
  const int j0 = blockIdx.y * 64;   // 0..6143

  const int tx = tid & 63, ty = tid >> 6;
#pragma unroll
  for (int r = 0; r < 64; r += 4)
    tile[r + ty][tx] = src[(size_t)(k0 + r + ty) * 6144 + j0 + tx];   // tile[k][j]
  __syncthreads();

  const int txk = (tid & 31) * 2;
  const int tyn = tid >> 5;
#pragma unroll
  for (int r = 0; r < 64; r += 8) {
    int jl = r + tyn;
    half2v p = {(_Float16)tile[txk][jl], (_Float16)tile[txk + 1][jl]};
    *(half2v*)&dst[(size_t)(j0 + jl) * 2048 + k0 + txk] = p;
  }
}

// ---------- r-gate: p = hard_sigmoid(x_r)*h ; A1r = p ; A2r = (j<2048 ? -p : p) ----------
__global__ __launch_bounds__(256) void rgate(const _Float16* __restrict__ xacc,
                                             const float* __restrict__ h,
                                             _Float16* __restrict__ A1r,
                                             _Float16* __restrict__ A2r) {
  int i = blockIdx.x * blockDim.x + threadIdx.x;   // 1M float4 groups
  int base = i * 4;
  int m = base >> 12;
  int j = base & 4095;
  float s = (j < 2048) ? -1.0f : 1.0f;
  half4v rp = *(const half4v*)&xacc[(size_t)m * 12288 + 4096 + j];
  float4 hv = *(const float4*)&h[base];
  float p0 = hsig((float)rp[0]) * hv.x;
  float p1 = hsig((float)rp[1]) * hv.y;
  float p2 = hsig((float)rp[2]) * hv.z;
  float p3 = hsig((float)rp[3]) * hv.w;
  half4v o1 = {(_Float16)p0, (_Float16)p1, (_Float16)p2, (_Float16)p3};
  half4v o2 = {(_Float16)(s * p0), (_Float16)(s * p1), (_Float16)(s * p2), (_Float16)(s * p3)};
  *(half4v*)&A1r[base] = o1;
  *(half4v*)&A2r[base] = o2;
}

// ---------- combine: out = z*h + (1-z)*tanh(xh + P0 + P1) ----------
__global__ __launch_bounds__(256) void combine(const _Float16* __restrict__ xacc,
                                               const _Float16* __restrict__ P0,
                                               const _Float16* __restrict__ P1,
                                               const float* __restrict__ h,
                                               float* __restrict__ out) {
  int i = blockIdx.x * blockDim.x + threadIdx.x;   // 1M float4 groups
  int base = i * 4;
  int m = base >> 12;
  int j = base & 4095;
  half4v zv = *(const half4v*)&xacc[(size_t)m * 12288 + j];
  half4v xh = *(const half4v*)&xacc[(size_t)m * 12288 + 8192 + j];
  half4v p0 = *(const half4v*)&P0[base];
  half4v p1 = *(const half4v*)&P1[base];
  float4 hv = *(const float4*)&h[base];
  float4 o;
  {
    float z = hsig((float)zv[0]); float t = tanhf((float)xh[0] + (float)p0[0] + (float)p1[0]);
    o.x = z * hv.x + (1.0f - z) * t;
  }
  {
    float z = hsig((float)zv[1]); float t = tanhf((float)xh[1] + (float)p0[1] + (float)p1[1]);
    o.y = z * hv.y + (1.0f - z) * t;
  }
  {
    float z = hsig((float)zv[2]); float t = tanhf((float)xh[2] + (float)p0[2] + (float)p1[2]);
    o.z = z * hv.z + (1.0f - z) * t;
  }
  {
    float z = hsig((float)zv[3]); float t = tanhf((float)xh[3] + (float)p0[3] + (float)p1[3]);
    o.w = z * hv.w + (1.0f - z) * t;
  }
  *(float4*)&out[base] = o;
}

// ---------- NEW: deep-pipelined fused GEMM for the big pass ----------
// C[1024 x 12288] tiles of BM=128 x BN=256, BK=32 substeps, 512 threads (8 waves
// as 2Mx4N, wave tile 64x64, acc[4][4] of 16x16x32 f16 MFMA).
// LDS: 96 KiB dynamic, 4-deep ring of K-subtiles: A 4 x (128x32) f16, B 4 x (256x32).
// Counted-vmcnt pipeline (T3/T4): stage(s+2) each substep -> s_waitcnt vmcnt(6)
// (own stage(s) landed; s+1,s+2 stay in flight across the barrier) -> raw
// s_barrier -> 8x ds_read_b128 -> setprio(1) -> 16 MFMA -> setprio(0).
// NO __syncthreads() in the loop (it would emit vmcnt(0) and drain the queue —
// that drain is the measured ~60% stall of the old 2-barrier structure).
// Staging keeps the conflict-free swizzle: linear LDS dest (global_load_lds
// requirement), pre-swizzled global source; slot = g ^ ((row^(row>>2))&3)
// (<=2-way bank aliasing on ds_read_b128 — free per m136).
// K phases: z/r cols: 4 phases (X*K then H*R, 8192 K total, NS=256);
// h cols: 2 phases (X*K, 4096 K, NS=128). Grid (48, 8) = 384 blocks; the 48
// columns/row with 48 % 8 == 0 means all 8 row-blocks of a column land on the
// same XCD -> automatic B-panel L2 reuse.
__global__ __launch_bounds__(512, 2) void gemm256(
    const _Float16* __restrict__ Ax1, const _Float16* __restrict__ Ax2,
    const _Float16* __restrict__ Ah1, const _Float16* __restrict__ Ah2,
    const _Float16* __restrict__ WKr, const _Float16* __restrict__ WKi,
    const _Float16* __restrict__ WRr, const _Float16* __restrict__ WRi,
    _Float16* __restrict__ xacc,
    const float* __restrict__ rbias, const float* __restrict__ ibias)
{
  extern __shared__ __align__(16) _Float16 smem[];   // 49152 f16 = 96 KiB
  const int tid  = threadIdx.x;
  const int lane = tid & 63;
  const int wave = tid >> 6;          // 0..7
  const int quad = lane >> 4;         // k-granule of the MFMA fragment
  const int r16  = lane & 15;
  const int wm = (wave >> 2) * 64;    // 0,64
  const int wn = (wave & 3) * 64;     // 0,64,128,192
  const int mbase = blockIdx.y * 128;
  const int nbase = blockIdx.x * 256;

  const int  gate   = nbase >> 12;
  const bool hi     = (nbase & 2048) != 0;
  const int  jprime = nbase & 2047;

  int nph;
  const _Float16 *pA0, *pA1, *pA2, *pA3;
  const _Float16 *pB0, *pB1, *pB2, *pB3;
  {
    const size_t browK = (size_t)(gate * 2048 + jprime) * 2048;
    const _Float16* Ax = hi ? Ax2 : Ax1;
    const _Float16* KL = hi ? WKi : WKr;
    const _Float16* KH = hi ? WKr : WKi;
    pA0 = Ax + (size_t)mbase * 4096;      pB0 = KL + browK;
    pA1 = pA0 + 2048;                     pB1 = KH + browK;
    if (gate < 2) {
      nph = 4;
      const _Float16* Ah = hi ? Ah2 : Ah1;
      const _Float16* RL = hi ? WRi : WRr;
      const _Float16* RH = hi ? WRr : WRi;
      pA2 = Ah + (size_t)mbase * 4096;    pB2 = RL + browK;
      pA3 = pA2 + 2048;                   pB3 = RH + browK;
    } else {
      nph = 2;
      pA2 = pA0; pB2 = pB0; pA3 = pA0; pB3 = pB0;   // never reached
    }
  }
  const int NS = nph * 64;   // substeps of K=32

  // per-thread staging geometry (loop-invariant).
  // A subtile: 512 granules of 16B: granule d = tid -> row=d>>2 (0..127), slot=d&3.
  // B subtile: 1024 granules: d = tid and tid+512 -> row=d>>2 (0..255).
  // global source granule g = slot ^ swz(row); LDS dest is linear (d*8 elems).
  const int arow_s = tid >> 2;
  const int ag     = (tid & 3) ^ ((arow_s ^ (arow_s >> 2)) & 3);
  const size_t aoff = (size_t)arow_s * 4096 + ag * 8;
  const int aldsd   = tid * 8;

  const int brow_s0 = tid >> 2;
  const int bg0     = (tid & 3) ^ ((brow_s0 ^ (brow_s0 >> 2)) & 3);
  const size_t boff0 = (size_t)brow_s0 * 2048 + bg0 * 8;
  const int bldsd0   = tid * 8;
  const int brow_s1 = brow_s0 + 128;
  const int bg1     = (tid & 3) ^ ((brow_s1 ^ (brow_s1 >> 2)) & 3);
  const size_t boff1 = (size_t)brow_s1 * 2048 + bg1 * 8;
  const int bldsd1   = (tid + 512) * 8;

#define STAGE(S2) do {                                                          \
    int p2_ = (S2) >> 6;                                                        \
    int kof_ = ((S2) & 63) * 32;                                                \
    int bb_ = (S2) & 3;                                                         \
    const _Float16* As_ = p2_ == 0 ? pA0 : p2_ == 1 ? pA1 : p2_ == 2 ? pA2 : pA3; \
    const _Float16* Bs_ = p2_ == 0 ? pB0 : p2_ == 1 ? pB1 : p2_ == 2 ? pB2 : pB3; \
    __builtin_amdgcn_global_load_lds(                                           \
        (__attribute__((address_space(1))) void*)(As_ + aoff + kof_),           \
        (__attribute__((address_space(3))) void*)&smem[bb_ * 4096 + aldsd], 16, 0, 0); \
    __builtin_amdgcn_global_load_lds(                                           \
        (__attribute__((address_space(1))) void*)(Bs_ + boff0 + kof_),          \
        (__attribute__((address_space(3))) void*)&smem[16384 + bb_ * 8192 + bldsd0], 16, 0, 0); \
    __builtin_amdgcn_global_load_lds(                                           \
        (__attribute__((address_space(1))) void*)(Bs_ + boff1 + kof_),          \
        (__attribute__((address_space(3))) void*)&smem[16384 + bb_ * 8192 + bldsd1], 16, 0, 0); \
  } while (0)

  float4v acc[4][4];
#pragma unroll
  for (int i = 0; i < 4; ++i)
#pragma unroll
    for (int j = 0; j < 4; ++j) acc[i][j] = (float4v){0.f, 0.f, 0.f, 0.f};

  // prologue: 2 subtiles in flight (6 loads/thread)
  STAGE(0);
  STAGE(1);

#pragma unroll 1
  for (int s = 0; s < NS; ++s) {
    if (s + 2 < NS) {
      STAGE(s + 2);
      // steady state: stage(s+1) + stage(s+2) = 6 loads stay in flight;
      // oldest (stage(s), our own) guaranteed complete. Never drains to 0.
      asm volatile("s_waitcnt vmcnt(6)" ::: "memory");
    } else if (s + 1 < NS) {
      asm volatile("s_waitcnt vmcnt(3)" ::: "memory");
    } else {
      asm volatile("s_waitcnt vmcnt(0)" ::: "memory");
    }
    __builtin_amdgcn_s_barrier();      // all waves' stage(s) now landed
    asm volatile("" ::: "memory");     // block hoisting ds_reads above barrier

    const int b = s & 3;
    half8 af[4], bf[4];
#pragma unroll
    for (int t = 0; t < 4; ++t) {
      int arow = wm + t * 16 + r16;
      af[t] = *(const half8*)&smem[b * 4096 +
                 (arow * 4 + (quad ^ ((arow ^ (arow >> 2)) & 3))) * 8];
      int brow = wn + t * 16 + r16;
      bf[t] = *(const half8*)&smem[16384 + b * 8192 +
                 (brow * 4 + (quad ^ ((brow ^ (brow >> 2)) & 3))) * 8];
    }
    __builtin_amdgcn_s_setprio(1);
#pragma unroll
    for (int mt = 0; mt < 4; ++mt)
#pragma unroll
      for (int nt = 0; nt < 4; ++nt)
        acc[mt][nt] = __builtin_amdgcn_mfma_f32_16x16x32_f16(af[mt], bf[nt], acc[mt][nt], 0, 0, 0);
    __builtin_amdgcn_s_setprio(0);
  }
#undef STAGE

  // epilogue: C/D layout col = lane&15, row = quad*4 + e
  const int mrow0 = mbase + wm + quad * 4;
  const int ncol0 = nbase + wn + r16;
#pragma unroll
  for (int nt = 0; nt < 4; ++nt) {
    int n = ncol0 + nt * 16;
    int g = n >> 12, j = n & 4095;
    float bia = (j < 2048) ? rbias[g * 2048 + j] : ibias[g * 2048 + j - 2048];
#pragma unroll
    for (int mt = 0; mt < 4; ++mt)
#pragma unroll
      for (int e = 0; e < 4; ++e) {
        int m = mrow0 + mt * 16 + e;
        xacc[(size_t)m * 12288 + n] = (_Float16)(acc[mt][nt][e] + bia);
      }
  }
}

// ---------- old fused GEMM, retained for the split-K (r*h)@Rh pass (FINAL=1) ----------
template<int FINAL>
__global__ __launch_bounds__(256, 3) void gemm_big(
    const _Float16* __restrict__ Ax1, const _Float16* __restrict__ Ax2,
    const _Float16* __restrict__ Ah1, const _Float16* __restrict__ Ah2,
    const _Float16* __restrict__ WKr, const _Float16* __restrict__ WKi,
    const _Float16* __restrict__ WRr, const _Float16* __restrict__ WRi,
    _Float16* __restrict__ xacc,
    _Float16* __restrict__ P0, _Float16* __restrict__ P1,
    const float* __restrict__ rbias, const float* __restrict__ ibias)
{
  __shared__ __align__(16) _Float16 lds[16384];   // 32 KB
  const int tid  = threadIdx.x;
  const int lane = tid & 63;
  const int wave = tid >> 6;
  const int quad = lane >> 4;
  const int r16  = lane & 15;
  const int wm = (wave >> 1) * 64;
  const int wn = (wave & 1) * 64;
  const int mbase = blockIdx.y * 128;
  const int nbase = blockIdx.x * 128;

  const int  gate   = nbase >> 12;
  const bool hi     = (nbase & 2048) != 0;
  const int  jprime = nbase & 2047;

  int nph;
  const _Float16* pA[4];
  const _Float16* pB[4];
  if (FINAL) {
    nph = 1;
    const _Float16* Ax = hi ? Ax2 : Ax1;
    const _Float16* BL = hi ? WKi : WKr;   // caller passes Rh row bases in WK slots
    const _Float16* BH = hi ? WKr : WKi;
    if (blockIdx.z == 0) {
      pA[0] = Ax + (size_t)mbase * 4096;
      pB[0] = BL + (size_t)jprime * 2048;
    } else {
      pA[0] = Ax + (size_t)mbase * 4096 + 2048;
      pB[0] = BH + (size_t)jprime * 2048;
    }
  } else {
    const size_t browK = (size_t)(gate * 2048 + jprime) * 2048;
    const _Float16* Ax = hi ? Ax2 : Ax1;
    const _Float16* KL = hi ? WKi : WKr;
    const _Float16* KH = hi ? WKr : WKi;
    pA[0] = Ax + (size_t)mbase * 4096;      pB[0] = KL + browK;
    pA[1] = pA[0] + 2048;                   pB[1] = KH + browK;
    if (gate < 2) {
      nph = 4;
      const _Float16* Ah = hi ? Ah2 : Ah1;
      const _Float16* RL = hi ? WRi : WRr;
      const _Float16* RH = hi ? WRr : WRi;
      pA[2] = Ah + (size_t)mbase * 4096;    pB[2] = RL + browK;
      pA[3] = pA[2] + 2048;                 pB[3] = RH + browK;
    } else {
      nph = 2;
    }
  }

  float4v acc[4][4];
#pragma unroll
  for (int i = 0; i < 4; ++i)
#pragma unroll
    for (int j = 0; j < 4; ++j) acc[i][j] = (float4v){0.f, 0.f, 0.f, 0.f};

  int offA[4], offB[4], ldsA[4], ldsB[4];
#pragma unroll
  for (int i = 0; i < 4; ++i) {
    int c = i * 256 + tid;          // granule chunk 0..1023
    int row = c >> 3;               // 0..127
    int sw = (c & 7) ^ (row & 7);   // XOR swizzle within row (R2 geometry, 0 conflicts)
    offA[i] = row * 4096 + sw * 8;  // A row stride 4096 elems
    offB[i] = row * 2048 + sw * 8;  // B row stride 2048 elems
    ldsA[i] = c * 8;
    ldsB[i] = 8192 + c * 8;
  }

#pragma unroll 1
  for (int p = 0; p < 4; ++p) {
    if (p >= nph) break;
    const _Float16* Ab = pA[p];
    const _Float16* Bb = pB[p];
#pragma unroll 1
    for (int it = 0; it < 32; ++it) {
#pragma unroll
      for (int i = 0; i < 4; ++i)
        __builtin_amdgcn_global_load_lds(
            (__attribute__((address_space(1))) void*)(Ab + offA[i]),
            (__attribute__((address_space(3))) void*)&lds[ldsA[i]], 16, 0, 0);
#pragma unroll
      for (int i = 0; i < 4; ++i)
        __builtin_amdgcn_global_load_lds(
            (__attribute__((address_space(1))) void*)(Bb + offB[i]),
            (__attribute__((address_space(3))) void*)&lds[ldsB[i]], 16, 0, 0);
      Ab += 64;
      Bb += 64;
      __syncthreads();
#pragma unroll
      for (int ks = 0; ks < 2; ++ks) {
        half8 af[4], bf[4];
        int akg = ks * 4 + quad;
#pragma unroll
        for (int t = 0; t < 4; ++t) {
          int arow = wm + t * 16 + r16;
          af[t] = *(const half8*)&lds[(arow * 8 + (akg ^ (arow & 7))) * 8];
          int brow = wn + t * 16 + r16;
          bf[t] = *(const half8*)&lds[8192 + (brow * 8 + (akg ^ (brow & 7))) * 8];
        }
#pragma unroll
        for (int mt = 0; mt < 4; ++mt)
#pragma unroll
          for (int nt = 0; nt < 4; ++nt)
            acc[mt][nt] = __builtin_amdgcn_mfma_f32_16x16x32_f16(af[mt], bf[nt], acc[mt][nt], 0, 0, 0);
      }
      __syncthreads();
    }
  }

  // epilogue: C/D layout col = lane&15, row = quad*4 + e
  const int mrow0 = mbase + wm + quad * 4;
  const int ncol0 = nbase + wn + r16;
  if (!FINAL) {
#pragma unroll
    for (int nt = 0; nt < 4; ++nt) {
      int n = ncol0 + nt * 16;
      int g = n >> 12, j = n & 4095;
      float b = (j < 2048) ? rbias[g * 2048 + j] : ibias[g * 2048 + j - 2048];
#pragma unroll
      for (int mt = 0; mt < 4; ++mt)
#pragma unroll
        for (int e = 0; e < 4; ++e) {
          int m = mrow0 + mt * 16 + e;
          xacc[(size_t)m * 12288 + n] = (_Float16)(acc[mt][nt][e] + b);
        }
    }
  } else {
    _Float16* P = blockIdx.z ? P1 : P0;
#pragma unroll
    for (int nt = 0; nt < 4; ++nt) {
      int n = ncol0 + nt * 16;
#pragma unroll
      for (int mt = 0; mt < 4; ++mt)
#pragma unroll
        for (int e = 0; e < 4; ++e) {
          int m = mrow0 + mt * 16 + e;
          P[(size_t)m * 4096 + n] = (_Float16)acc[mt][nt][e];
        }
    }
  }
}

// ---------- launch ----------
extern "C" void kernel_launch(void* const* d_in, const int* in_sizes, int n_in,
                              void* d_out, int out_size, void* d_ws, size_t ws_size,
                              hipStream_t stream) {
  const float* inputs = (const float*)d_in[0];
  const float* h_tm1  = (const float*)d_in[1];
  const float* rk     = (const float*)d_in[2];
  const float* ik     = (const float*)d_in[3];
  const float* rrk    = (const float*)d_in[4];
  const float* irk    = (const float*)d_in[5];
  const float* rb     = (const float*)d_in[6];
  const float* ib     = (const float*)d_in[7];
  float* out = (float*)d_out;

  char* ws = (char*)d_ws;
  // ws layout (bytes), total 159,383,552 (~152 MiB):
  _Float16* WrK  = (_Float16*)(ws + 0);           // 6144*2048*2 = 25,165,824
  _Float16* WiK  = (_Float16*)(ws + 25165824);
  _Float16* WrR  = (_Float16*)(ws + 50331648);
  _Float16* WiR  = (_Float16*)(ws + 75497472);
  _Float16* A1x  = (_Float16*)(ws + 100663296);   // 1024*4096*2 = 8,388,608
  _Float16* A2x  = (_Float16*)(ws + 109051904);
  _Float16* A1h  = (_Float16*)(ws + 117440512);
  _Float16* A2h  = (_Float16*)(ws + 125829120);
  _Float16* xacc = (_Float16*)(ws + 134217728);   // 1024*12288*2 = 25,165,824
  _Float16* A1r  = A1x;   // alias: inputs-f16 dead after the fused GEMM
  _Float16* A2r  = A2x;
  _Float16* P0   = A1h;   // alias: h-f16 dead after the fused GEMM
  _Float16* P1   = A2h;

  cvt_pair<<<4096, 256, 0, stream>>>(inputs, A1x, A2x);
  cvt_pair<<<4096, 256, 0, stream>>>(h_tm1, A1h, A2h);
  transpose_cast<<<dim3(32, 96, 4), 256, 0, stream>>>(rk, ik, rrk, irk, WrK, WiK, WrR, WiR);
  // fused: x_z+h@Rz+bz, x_r+h@Rr+br (K=8192), x_h+bh (K=4096)  (N = 12288)
  // deep-pipelined 128x256 tiles, 96 KiB dynamic LDS, counted-vmcnt schedule.
  gemm256<<<dim3(48, 8), 512, 98304, stream>>>(A1x, A2x, A1h, A2h, WrK, WiK, WrR, WiR,
                                               xacc, rb, ib);
  // rh = hard_sigmoid(x_r + h@Rr) * h_tm1  (both sign variants)
  rgate<<<4096, 256, 0, stream>>>(xacc, h_tm1, A1r, A2r);
  // split-K partials of (r*h) @ Rh  (N = 4096, K halves -> P0/P1)
  gemm_big<1><<<dim3(32, 8, 2), 256, 0, stream>>>(A1r, A2r, nullptr, nullptr,
                                                  WrR + (size_t)4096 * 2048,
                                                  WiR + (size_t)4096 * 2048,
                                                  nullptr, nullptr, nullptr, P0, P1,
                                                  nullptr, nullptr);
  // h = z*h_tm1 + (1-z)*tanh(x_h + P0 + P1)
  combine<<<4096, 256, 0, stream>>>(xacc, P0, P1, h_tm1, out);
}

// Round 2
// 551.493 us; speedup vs baseline: 1.1079x; 1.1079x over previous
//
#include <hip/hip_runtime.h>

// ---------- types ----------
typedef _Float16 half8  __attribute__((ext_vector_type(8)));
typedef _Float16 half4v __attribute__((ext_vector_type(4)));
typedef _Float16 half2v __attribute__((ext_vector_type(2)));
typedef float    float4v __attribute__((ext_vector_type(4)));

__device__ __forceinline__ float hsig(float x) {
  return fminf(fmaxf(fmaf(x, 0.2f, 0.5f), 0.0f), 1.0f);
}

__device__ __forceinline__ half2v pk2(float a, float b) {
  half2v r; r[0] = (_Float16)a; r[1] = (_Float16)b; return r;
}

// ============================================================================
// Gauss 3-mult complex GEMM:  a=Xr b=Xi c=Wr d=Wi
//   m1 = a@(c-d), m2 = b@(c+d), m3 = (a+b)@d ;  Re = m1+m3, Im = m2-m3
// Panels: for each A-matrix we prep {r-half, i-half, sum} as 1024x2048 f16.
// Weights: per side {Wd=T(r-i), Ws=T(r+i), Wi=T(i)}, each 6144x2048 f16.
// ============================================================================

// ---------- prep: A panels for X and H: Pr=f16(lo), Pi=f16(hi), Ps=f16(lo+hi) ----------
__global__ __launch_bounds__(256) void prep_a(const float* __restrict__ x,
                                              const float* __restrict__ h,
                                              _Float16* __restrict__ PXr, _Float16* __restrict__ PXi,
                                              _Float16* __restrict__ PXs, _Float16* __restrict__ PHr,
                                              _Float16* __restrict__ PHi, _Float16* __restrict__ PHs) {
  int i = blockIdx.x * 256 + threadIdx.x;      // 524288 float4 groups per tensor
  const float* src; _Float16 *Pr, *Pi, *Ps;
  if (blockIdx.y == 0) { src = x; Pr = PXr; Pi = PXi; Ps = PXs; }
  else                 { src = h; Pr = PHr; Pi = PHi; Ps = PHs; }
  int base = i * 4;
  int m = base >> 11, j = base & 2047;
  float4 a  = *(const float4*)&src[(size_t)m * 4096 + j];
  float4 bv = *(const float4*)&src[(size_t)m * 4096 + 2048 + j];
  size_t o = (size_t)m * 2048 + j;
  half4v hr, hi2, hs;
  hr[0]=(_Float16)a.x;  hr[1]=(_Float16)a.y;  hr[2]=(_Float16)a.z;  hr[3]=(_Float16)a.w;
  hi2[0]=(_Float16)bv.x; hi2[1]=(_Float16)bv.y; hi2[2]=(_Float16)bv.z; hi2[3]=(_Float16)bv.w;
  hs[0]=(_Float16)(a.x+bv.x); hs[1]=(_Float16)(a.y+bv.y);
  hs[2]=(_Float16)(a.z+bv.z); hs[3]=(_Float16)(a.w+bv.w);
  *(half4v*)&Pr[o] = hr;
  *(half4v*)&Pi[o] = hi2;
  *(half4v*)&Ps[o] = hs;
}

// ---------- prep: transpose+cast weight combos (2048x6144 f32 pairs -> 3x 6144x2048 f16) ----------
__global__ __launch_bounds__(256) void transpose_cast3(
    const float* __restrict__ rkK, const float* __restrict__ ikK,
    const float* __restrict__ rkR, const float* __restrict__ ikR,
    _Float16* __restrict__ WdK, _Float16* __restrict__ WsK, _Float16* __restrict__ WiK,
    _Float16* __restrict__ WdR, _Float16* __restrict__ WsR, _Float16* __restrict__ WiR) {
  __shared__ float tr[64][65];
  __shared__ float ti[64][65];
  const float* rs  = blockIdx.z ? rkR : rkK;
  const float* is2 = blockIdx.z ? ikR : ikK;
  _Float16* Wd = blockIdx.z ? WdR : WdK;
  _Float16* Ws = blockIdx.z ? WsR : WsK;
  _Float16* Wi = blockIdx.z ? WiR : WiK;
  const int tid = threadIdx.x;
  const int k0 = blockIdx.x * 64;   // 0..2047
  const int j0 = blockIdx.y * 64;   // 0..6143
  const int tx = tid & 63, ty = tid >> 6;
#pragma unroll
  for (int r = 0; r < 64; r += 4) {
    size_t so = (size_t)(k0 + r + ty) * 6144 + j0 + tx;
    tr[r + ty][tx] = rs[so];
    ti[r + ty][tx] = is2[so];
  }
  __syncthreads();
  const int txk = (tid & 31) * 2;
  const int tyn = tid >> 5;
#pragma unroll
  for (int r = 0; r < 64; r += 8) {
    int jl = r + tyn;
    float r0 = tr[txk][jl], r1 = tr[txk + 1][jl];
    float i0 = ti[txk][jl], i1 = ti[txk + 1][jl];
    size_t dof = (size_t)(j0 + jl) * 2048 + k0 + txk;
    *(half2v*)&Wd[dof] = pk2(r0 - i0, r1 - i1);
    *(half2v*)&Ws[dof] = pk2(r0 + i0, r1 + i1);
    *(half2v*)&Wi[dof] = pk2(i0, i1);
  }
}

// ---------- one K=64-per-iter GEMM phase (R0's proven inner loop, A-stride 2048) ----------
__device__ __forceinline__ void run_phase(const _Float16* Ab, const _Float16* Bb, int nit,
                                          _Float16* lds, int tid, int wm, int wn,
                                          int quad, int r16, float4v (&acc)[4][4]) {
  int off[4], ldsA[4], ldsB[4];
#pragma unroll
  for (int i = 0; i < 4; ++i) {
    int c = i * 256 + tid;          // granule chunk 0..1023
    int row = c >> 3;               // 0..127
    int sw = (c & 7) ^ (row & 7);   // XOR swizzle (R2-verified conflict-free geometry)
    off[i]  = row * 2048 + sw * 8;  // A and B row stride both 2048 elems
    ldsA[i] = c * 8;
    ldsB[i] = 8192 + c * 8;
  }
#pragma unroll 1
  for (int it = 0; it < nit; ++it) {
#pragma unroll
    for (int i = 0; i < 4; ++i)
      __builtin_amdgcn_global_load_lds(
          (__attribute__((address_space(1))) void*)(Ab + off[i]),
          (__attribute__((address_space(3))) void*)&lds[ldsA[i]], 16, 0, 0);
#pragma unroll
    for (int i = 0; i < 4; ++i)
      __builtin_amdgcn_global_load_lds(
          (__attribute__((address_space(1))) void*)(Bb + off[i]),
          (__attribute__((address_space(3))) void*)&lds[ldsB[i]], 16, 0, 0);
    Ab += 64;
    Bb += 64;
    __syncthreads();
#pragma unroll
    for (int ks = 0; ks < 2; ++ks) {
      half8 af[4], bf[4];
      int akg = ks * 4 + quad;
#pragma unroll
      for (int t = 0; t < 4; ++t) {
        int arow = wm + t * 16 + r16;
        af[t] = *(const half8*)&lds[(arow * 8 + (akg ^ (arow & 7))) * 8];
        int brow = wn + t * 16 + r16;
        bf[t] = *(const half8*)&lds[8192 + (brow * 8 + (akg ^ (brow & 7))) * 8];
      }
#pragma unroll
      for (int mt = 0; mt < 4; ++mt)
#pragma unroll
        for (int nt = 0; nt < 4; ++nt)
          acc[mt][nt] = __builtin_amdgcn_mfma_f32_16x16x32_f16(af[mt], bf[nt], acc[mt][nt], 0, 0, 0);
    }
    __syncthreads();
  }
}

// ---------- epilogue tile write: dst = acc + ssign*stash + bias ----------
__device__ __forceinline__ void write_tile(_Float16* __restrict__ dst, int ldc, int colbase,
    int mrow0, int ncol0, const float4v (&acc)[4][4], const half2v (&stash)[4][4][2],
    float ssign, const float* __restrict__ bias, int bbase) {
#pragma unroll
  for (int nt = 0; nt < 4; ++nt) {
    int nl = ncol0 + nt * 16;
    float bv = bias ? bias[bbase + nl] : 0.0f;
#pragma unroll
    for (int mt = 0; mt < 4; ++mt)
#pragma unroll
      for (int e = 0; e < 4; ++e) {
        float sv = (float)stash[mt][nt][e >> 1][e & 1];
        int m = mrow0 + mt * 16 + e;
        dst[(size_t)m * ldc + colbase + nl] = (_Float16)(acc[mt][nt][e] + ssign * sv + bv);
      }
  }
}

// ---------- Gauss GEMM ----------
// MODE 0: main pass, grid 640 uniform blocks (3 sections x 32 iters, K=2048 each):
//   512 heavy-halves: gate z/r x side {X(K-weights)->xaccX, H(R-weights)->xaccH}
//   128 light: gate h, X-side only.
//   Block: sec0 m3 -> stash(f16x2 in 32 VGPR) -> sec1 m1 -> Re tile -> sec2 m2 -> Im tile.
// MODE 1: (r*h)@Rh, grid 512, split-K z=0..3 (K=512, 3 sections x 8 iters) -> P0..P3.
// Bijective XCD swizzle (grid%8==0): row-sharing blocks land on one XCD for B-panel L2 reuse.
template<int MODE>
__global__ __launch_bounds__(256, 3) void gemm_gauss(
    const _Float16* __restrict__ WdK, const _Float16* __restrict__ WsK, const _Float16* __restrict__ WiK,
    const _Float16* __restrict__ WdR, const _Float16* __restrict__ WsR, const _Float16* __restrict__ WiR,
    const _Float16* __restrict__ PXr, const _Float16* __restrict__ PXi, const _Float16* __restrict__ PXs,
    const _Float16* __restrict__ PHr, const _Float16* __restrict__ PHi, const _Float16* __restrict__ PHs,
    _Float16* __restrict__ xaccX, _Float16* __restrict__ xaccH,
    _Float16* __restrict__ P0, _Float16* __restrict__ P1,
    _Float16* __restrict__ P2, _Float16* __restrict__ P3,
    const float* __restrict__ rbias, const float* __restrict__ ibias) {
  __shared__ __align__(16) _Float16 lds[16384];   // 32 KB -> 3 blocks/CU
  const int tid  = threadIdx.x;
  const int lane = tid & 63;
  const int wave = tid >> 6;
  const int quad = lane >> 4;
  const int r16  = lane & 15;
  const int wm = (wave >> 1) * 64;
  const int wn = (wave & 1) * 64;

  const int NWG = MODE ? 512 : 640;
  int b = blockIdx.x;
  int wid = (b & 7) * (NWG >> 3) + (b >> 3);    // bijective XCD swizzle

  int gate, jb, row, nit;
  const _Float16 *A0, *A1, *A2, *B0, *B1, *B2;
  _Float16* dst; int ldc, colRe, bbase;
  const float *rb2, *ib2;

  if (MODE == 0) {
    nit = 32;
    int side;
    if (wid < 512) { gate = wid >> 8; side = (wid >> 7) & 1; jb = (wid >> 3) & 15; row = wid & 7; }
    else { int t = wid - 512; gate = 2; side = 0; jb = (t >> 3) & 15; row = t & 7; }
    size_t boff = (size_t)(gate * 2048 + jb * 128) * 2048;
    size_t aoff = (size_t)(row * 128) * 2048;
    if (side == 0) {
      A0 = PXs + aoff; A1 = PXr + aoff; A2 = PXi + aoff;
      B0 = WiK + boff; B1 = WdK + boff; B2 = WsK + boff;
      dst = xaccX; ldc = 12288;
      rb2 = rbias; ib2 = ibias;
    } else {
      A0 = PHs + aoff; A1 = PHr + aoff; A2 = PHi + aoff;
      B0 = WiR + boff; B1 = WdR + boff; B2 = WsR + boff;
      dst = xaccH; ldc = 8192;
      rb2 = nullptr; ib2 = nullptr;
    }
    colRe = gate * 4096 + jb * 128;
    bbase = gate * 2048 + jb * 128;
  } else {
    nit = 8;
    int z = wid >> 7; int t = wid & 127;
    jb = (t >> 3) & 15; row = t & 7;
    int koff = z * 512;
    size_t boff = (size_t)(4096 + jb * 128) * 2048 + koff;   // h-gate rows of R weights
    size_t aoff = (size_t)(row * 128) * 2048 + koff;
    A0 = PXs + aoff; A1 = PXr + aoff; A2 = PXi + aoff;       // launch passes PR panels here
    B0 = WiR + boff; B1 = WdR + boff; B2 = WsR + boff;
    dst = (z == 0) ? P0 : (z == 1) ? P1 : (z == 2) ? P2 : P3;
    ldc = 4096; colRe = jb * 128; bbase = 0;
    gate = 0; rb2 = nullptr; ib2 = nullptr;
  }

  float4v acc[4][4];
#pragma unroll
  for (int i = 0; i < 4; ++i)
#pragma unroll
    for (int j = 0; j < 4; ++j) acc[i][j] = (float4v){0.f, 0.f, 0.f, 0.f};

  // sec0: m3 = S @ Wi  -> stash
  run_phase(A0, B0, nit, lds, tid, wm, wn, quad, r16, acc);
  half2v stash[4][4][2];
#pragma unroll
  for (int mt = 0; mt < 4; ++mt)
#pragma unroll
    for (int nt = 0; nt < 4; ++nt) {
      stash[mt][nt][0] = pk2(acc[mt][nt][0], acc[mt][nt][1]);
      stash[mt][nt][1] = pk2(acc[mt][nt][2], acc[mt][nt][3]);
      acc[mt][nt] = (float4v){0.f, 0.f, 0.f, 0.f};
    }

  const int mrow0 = row * 128 + wm + quad * 4;
  const int ncol0 = wn + r16;

  // sec1: m1 = a @ (c-d) ;  Re = m1 + m3 (+rbias)
  run_phase(A1, B1, nit, lds, tid, wm, wn, quad, r16, acc);
  write_tile(dst, ldc, colRe, mrow0, ncol0, acc, stash, 1.0f, rb2, bbase);

#pragma unroll
  for (int mt = 0; mt < 4; ++mt)
#pragma unroll
    for (int nt = 0; nt < 4; ++nt) acc[mt][nt] = (float4v){0.f, 0.f, 0.f, 0.f};

  // sec2: m2 = b @ (c+d) ;  Im = m2 - m3 (+ibias)
  run_phase(A2, B2, nit, lds, tid, wm, wn, quad, r16, acc);
  write_tile(dst, ldc, colRe + 2048, mrow0, ncol0, acc, stash, -1.0f, ib2, bbase);
}

// ---------- r-gate: r = hsig(xaccX_r + xaccH_r); panels of r*h ----------
__global__ __launch_bounds__(256) void rgate3(const _Float16* __restrict__ xaccX,
                                              const _Float16* __restrict__ xaccH,
                                              const float* __restrict__ h,
                                              _Float16* __restrict__ PRr,
                                              _Float16* __restrict__ PRi,
                                              _Float16* __restrict__ PRs) {
  int i = blockIdx.x * 256 + threadIdx.x;   // 524288 groups
  int base = i * 4;
  int m = base >> 11, j = base & 2047;
  half4v a1 = *(const half4v*)&xaccX[(size_t)m * 12288 + 4096 + j];
  half4v a2 = *(const half4v*)&xaccH[(size_t)m * 8192 + 4096 + j];
  half4v b1 = *(const half4v*)&xaccX[(size_t)m * 12288 + 4096 + 2048 + j];
  half4v b2 = *(const half4v*)&xaccH[(size_t)m * 8192 + 4096 + 2048 + j];
  float4 h1 = *(const float4*)&h[(size_t)m * 4096 + j];
  float4 h2 = *(const float4*)&h[(size_t)m * 4096 + 2048 + j];
  float p1[4], p2[4];
  p1[0] = hsig((float)a1[0] + (float)a2[0]) * h1.x;
  p1[1] = hsig((float)a1[1] + (float)a2[1]) * h1.y;
  p1[2] = hsig((float)a1[2] + (float)a2[2]) * h1.z;
  p1[3] = hsig((float)a1[3] + (float)a2[3]) * h1.w;
  p2[0] = hsig((float)b1[0] + (float)b2[0]) * h2.x;
  p2[1] = hsig((float)b1[1] + (float)b2[1]) * h2.y;
  p2[2] = hsig((float)b1[2] + (float)b2[2]) * h2.z;
  p2[3] = hsig((float)b1[3] + (float)b2[3]) * h2.w;
  size_t o = (size_t)m * 2048 + j;
  half4v orr, oi, os;
#pragma unroll
  for (int e = 0; e < 4; ++e) {
    orr[e] = (_Float16)p1[e];
    oi[e]  = (_Float16)p2[e];
    os[e]  = (_Float16)(p1[e] + p2[e]);
  }
  *(half4v*)&PRr[o] = orr;
  *(half4v*)&PRi[o] = oi;
  *(half4v*)&PRs[o] = os;
}

// ---------- combine: out = z*h + (1-z)*tanh(xh + P0+P1+P2+P3) ----------
__global__ __launch_bounds__(256) void combine4(const _Float16* __restrict__ xaccX,
                                                const _Float16* __restrict__ xaccH,
                                                const _Float16* __restrict__ P0,
                                                const _Float16* __restrict__ P1,
                                                const _Float16* __restrict__ P2,
                                                const _Float16* __restrict__ P3,
                                                const float* __restrict__ h,
                                                float* __restrict__ out) {
  int i = blockIdx.x * 256 + threadIdx.x;   // 1M float4 groups
  int base = i * 4;
  int m = base >> 12;
  int j = base & 4095;
  half4v zx = *(const half4v*)&xaccX[(size_t)m * 12288 + j];
  half4v zh = *(const half4v*)&xaccH[(size_t)m * 8192 + j];
  half4v xh = *(const half4v*)&xaccX[(size_t)m * 12288 + 8192 + j];
  half4v p0 = *(const half4v*)&P0[base];
  half4v p1 = *(const half4v*)&P1[base];
  half4v p2 = *(const half4v*)&P2[base];
  half4v p3 = *(const half4v*)&P3[base];
  float4 hv = *(const float4*)&h[base];
  float4 o;
  {
    float z = hsig((float)zx[0] + (float)zh[0]);
    float t = tanhf((float)xh[0] + (float)p0[0] + (float)p1[0] + (float)p2[0] + (float)p3[0]);
    o.x = z * hv.x + (1.0f - z) * t;
  }
  {
    float z = hsig((float)zx[1] + (float)zh[1]);
    float t = tanhf((float)xh[1] + (float)p0[1] + (float)p1[1] + (float)p2[1] + (float)p3[1]);
    o.y = z * hv.y + (1.0f - z) * t;
  }
  {
    float z = hsig((float)zx[2] + (float)zh[2]);
    float t = tanhf((float)xh[2] + (float)p0[2] + (float)p1[2] + (float)p2[2] + (float)p3[2]);
    o.z = z * hv.z + (1.0f - z) * t;
  }
  {
    float z = hsig((float)zx[3] + (float)zh[3]);
    float t = tanhf((float)xh[3] + (float)p0[3] + (float)p1[3] + (float)p2[3] + (float)p3[3]);
    o.w = z * hv.w + (1.0f - z) * t;
  }
  *(float4*)&out[base] = o;
}

// ---------- launch ----------
extern "C" void kernel_launch(void* const* d_in, const int* in_sizes, int n_in,
                              void* d_out, int out_size, void* d_ws, size_t ws_size,
                              hipStream_t stream) {
  const float* inputs = (const float*)d_in[0];
  const float* h_tm1  = (const float*)d_in[1];
  const float* rk     = (const float*)d_in[2];
  const float* ik     = (const float*)d_in[3];
  const float* rrk    = (const float*)d_in[4];
  const float* irk    = (const float*)d_in[5];
  const float* rb     = (const float*)d_in[6];
  const float* ib     = (const float*)d_in[7];
  float* out = (float*)d_out;

  char* ws = (char*)d_ws;
  // ws layout (bytes), peak 218,103,808 (~208 MiB):
  _Float16* WdK = (_Float16*)(ws + 0);            // 6144*2048*2 = 25,165,824 each
  _Float16* WsK = (_Float16*)(ws + 25165824);
  _Float16* WiK = (_Float16*)(ws + 50331648);
  _Float16* WdR = (_Float16*)(ws + 75497472);
  _Float16* WsR = (_Float16*)(ws + 100663296);
  _Float16* WiR = (_Float16*)(ws + 125829120);
  _Float16* PXr = (_Float16*)(ws + 150994944);    // 1024*2048*2 = 4,194,304 each
  _Float16* PXi = (_Float16*)(ws + 155189248);
  _Float16* PXs = (_Float16*)(ws + 159383552);
  _Float16* PHr = (_Float16*)(ws + 163577856);
  _Float16* PHi = (_Float16*)(ws + 167772160);
  _Float16* PHs = (_Float16*)(ws + 171966464);
  _Float16* xaccX = (_Float16*)(ws + 176160768);  // 1024*12288*2 = 25,165,824
  _Float16* xaccH = (_Float16*)(ws + 201326592);  // 1024*8192*2  = 16,777,216
  // aliases (dead data reuse):
  _Float16* PRr = PXr;                            // X panels dead after main gemm
  _Float16* PRi = PXi;
  _Float16* PRs = PXs;
  _Float16* P0  = (_Float16*)(ws + 0);            // K-side weights dead after main gemm
  _Float16* P1  = (_Float16*)(ws + 8388608);      // 1024*4096*2 = 8,388,608 each
  _Float16* P2  = (_Float16*)(ws + 16777216);
  _Float16* P3  = (_Float16*)(ws + 25165824);

  prep_a<<<dim3(2048, 2), 256, 0, stream>>>(inputs, h_tm1, PXr, PXi, PXs, PHr, PHi, PHs);
  transpose_cast3<<<dim3(32, 96, 2), 256, 0, stream>>>(rk, ik, rrk, irk,
                                                       WdK, WsK, WiK, WdR, WsR, WiR);
  // main: 640 uniform blocks; X-side -> xaccX (with bias), H-side -> xaccH
  gemm_gauss<0><<<640, 256, 0, stream>>>(WdK, WsK, WiK, WdR, WsR, WiR,
                                         PXr, PXi, PXs, PHr, PHi, PHs,
                                         xaccX, xaccH,
                                         nullptr, nullptr, nullptr, nullptr, rb, ib);
  rgate3<<<2048, 256, 0, stream>>>(xaccX, xaccH, h_tm1, PRr, PRi, PRs);
  // (r*h)@Rh, Gauss + split-K=4 -> P0..P3
  gemm_gauss<1><<<512, 256, 0, stream>>>(WdK, WsK, WiK, WdR, WsR, WiR,
                                         PRr, PRi, PRs, nullptr, nullptr, nullptr,
                                         nullptr, nullptr, P0, P1, P2, P3,
                                         nullptr, nullptr);
  combine4<<<4096, 256, 0, stream>>>(xaccX, xaccH, P0, P1, P2, P3, h_tm1, out);
}